// Round 9
// baseline (155.577 us; speedup 1.0000x reference)
//
#include <hip/hip_runtime.h>
#include <hip/hip_bf16.h>

// Problem constants (fixed by the reference).
#define N_NODES 10000
#define DEG     32
#define CH      16
#define IN_DIM  4
#define BATCH   8
#define E_EDGES (N_NODES * DEG)        // 320000
#define WI_STRIDE (E_EDGES * CH)       // 5,120,000 floats between w[i] planes
#define P_COUNT 625                    // 512*625 == E_EDGES : gather period in n
#define LX_STRIDE 36                   // 32 floats/row + 4 pad (16B-aligned)

// Kernel 1: transpose/pad x[B][N][4] -> xt[N+1][B][4] (node-major, 128 B/node).
__global__ __launch_bounds__(256) void lcg_transpose(const float* __restrict__ x,
                                                     float* __restrict__ xt) {
    int t = blockIdx.x * 256 + threadIdx.x;
    if (t < BATCH * N_NODES) {
        int b = t / N_NODES;
        int node = t - b * N_NODES;
        float4 v = *(const float4*)(x + 4 * t);          // x[b][node][0..3]
        *(float4*)(xt + node * 32 + b * 4) = v;
    } else if (t < BATCH * N_NODES + 8) {
        int r = t - BATCH * N_NODES;                     // zero pad row N_NODES
        *(float4*)(xt + N_NODES * 32 + r * 4) = make_float4(0.f, 0.f, 0.f, 0.f);
    }
}

// Kernel 2: block = (p, j-half), 512 threads = 8 waves; wave wv owns
// j = 8*jh + wv (n = p + 625*j).
// r2-r8 were bulk-synchronous: gather-all -> sync -> compute-all, so the
// TA/L2 gather phase, the DS phase and the weight HBM stream ran SERIALLY
// (~9 + ~12 + ~13 us ~= the stubborn 35 us). v9 double-buffers the x-chunk
// per ds iteration so all three pipes run concurrently:
//   iter ds: load weights(ds+1-prefetched), issue gather(chunk ds+1),
//            compute chunk ds from LDS, write gathered chunk, one sync.
// Chunk = 64 rows (s = 64 ds + 16 dq + c). LDS 2*64*36*4 = 18.4 KB ->
// 4 blocks/CU = 32 waves/CU. Weight loads stay 64-float contiguous per
// wave instruction (the r6 win).
__global__ __launch_bounds__(512, 4) void lcg_main(
    const float* __restrict__ xt,     // [N+1][32]
    const int*   __restrict__ edges,  // [E]
    const float* __restrict__ w,      // [4][E][16]
    float*       __restrict__ out)    // [8][N][16]
{
    __shared__ float lx[2][64 * LX_STRIDE];   // 2 x 9216 B

    int bid = blockIdx.x;
    int p   = bid >> 1;               // 0..624
    int jh  = bid & 1;                // j-half
    int t   = threadIdx.x;

    // gather mapping: thread t -> chunk row rg, float4 slot sub
    int sub = t & 7;
    int rg  = t >> 3;                 // 0..63
    const int* ep = edges + 512 * p;

    // compute mapping
    int lane = t & 63;
    int wv   = t >> 6;                // 0..7
    int c    = lane & 15;
    int dq   = lane >> 4;             // 0..3 : handles d = 4*ds + dq
    int n    = p + P_COUNT * (8 * jh + wv);

    // weight address: w[i][32n + (4ds+dq)][c] = base_i + n*512 + 64*ds + lane
    const float* wb = w + n * (DEG * CH) + lane;

    float acc[BATCH];
#pragma unroll
    for (int b = 0; b < BATCH; b++) acc[b] = 0.0f;

    // ---- prologue: gather chunk 0, prefetch weights for ds=0 ----
    {
        int nd0 = ep[rg];
        float4 g0 = *(const float4*)(xt + nd0 * 32 + sub * 4);
        *(float4*)(&lx[0][rg * LX_STRIDE + sub * 4]) = g0;
    }
    float wc0 = wb[0];
    float wc1 = wb[WI_STRIDE];
    float wc2 = wb[2 * WI_STRIDE];
    float wc3 = wb[3 * WI_STRIDE];
    __syncthreads();

#pragma unroll
    for (int ds = 0; ds < 8; ds++) {
        // prefetch next weights (clamped, wave-uniform ordering: issue first)
        int dsn = ds < 7 ? ds + 1 : 7;
        float wn0 = wb[64 * dsn];
        float wn1 = wb[64 * dsn + WI_STRIDE];
        float wn2 = wb[64 * dsn + 2 * WI_STRIDE];
        float wn3 = wb[64 * dsn + 3 * WI_STRIDE];

        // issue next chunk's gather (overlaps with compute below)
        float4 g;
        if (ds < 7) {
            int nd = ep[64 * (ds + 1) + rg];
            g = *(const float4*)(xt + nd * 32 + sub * 4);
        }

        // compute chunk ds from LDS buffer ds&1
        const float* lr = &lx[ds & 1][(16 * dq + c) * LX_STRIDE];
#pragma unroll
        for (int b = 0; b < BATCH; b++) {
            float4 xq = *(const float4*)(lr + 4 * b);
            acc[b] += xq.x * wc0 + xq.y * wc1 + xq.z * wc2 + xq.w * wc3;
        }
        wc0 = wn0; wc1 = wn1; wc2 = wn2; wc3 = wn3;

        // stage gathered chunk into the other buffer; one sync per iter
        if (ds < 7) {
            *(float4*)(&lx[(ds + 1) & 1][rg * LX_STRIDE + sub * 4]) = g;
            __syncthreads();
        }
    }

    // reduce over dq groups (lanes l, l^16, l^32, l^48)
#pragma unroll
    for (int b = 0; b < BATCH; b++) {
        acc[b] += __shfl_xor(acc[b], 16, 64);
        acc[b] += __shfl_xor(acc[b], 32, 64);
    }

    // dq group g stores batches {2g, 2g+1} (16 c-lanes = one 64 B line per b)
    int ob = n * CH + c;
    out[(2 * dq + 0) * (N_NODES * CH) + ob] = acc[2 * dq + 0];
    out[(2 * dq + 1) * (N_NODES * CH) + ob] = acc[2 * dq + 1];
}

extern "C" void kernel_launch(void* const* d_in, const int* in_sizes, int n_in,
                              void* d_out, int out_size, void* d_ws, size_t ws_size,
                              hipStream_t stream) {
    const float* x     = (const float*)d_in[0];   // [8][10000][4] f32
    const int*   edges = (const int*)d_in[1];     // [320000] int
    const float* w     = (const float*)d_in[2];   // [4][320000][16] f32
    float* out = (float*)d_out;                   // [8][10000][16] f32
    float* xt  = (float*)d_ws;                    // (10001*32) floats = 1.28 MB

    int tr_total  = BATCH * N_NODES + 8;                  // 80008
    int tr_blocks = (tr_total + 255) / 256;               // 313
    lcg_transpose<<<tr_blocks, 256, 0, stream>>>(x, xt);

    lcg_main<<<2 * P_COUNT, 512, 0, stream>>>(xt, edges, w, out);
}

// Round 10
// 129.869 us; speedup vs baseline: 1.1980x; 1.1980x over previous
//
#include <hip/hip_runtime.h>
#include <hip/hip_bf16.h>

// Problem constants (fixed by the reference).
#define N_NODES 10000
#define DEG     32
#define CH      16
#define IN_DIM  4
#define BATCH   8
#define E_EDGES (N_NODES * DEG)        // 320000
#define WI_STRIDE (E_EDGES * CH)       // 5,120,000 floats between w[i] planes
#define P_COUNT 625                    // 512*625 == E_EDGES : gather period in n
#define LX_STRIDE 36                   // 32 floats/row + 4 pad (16B-aligned)

// Kernel 1: transpose/pad x[B][N][4] -> xt[N+1][B][4] (node-major, 128 B/node).
__global__ __launch_bounds__(256) void lcg_transpose(const float* __restrict__ x,
                                                     float* __restrict__ xt) {
    int t = blockIdx.x * 256 + threadIdx.x;
    if (t < BATCH * N_NODES) {
        int b = t / N_NODES;
        int node = t - b * N_NODES;
        float4 v = *(const float4*)(x + 4 * t);          // x[b][node][0..3]
        *(float4*)(xt + node * 32 + b * 4) = v;
    } else if (t < BATCH * N_NODES + 8) {
        int r = t - BATCH * N_NODES;                     // zero pad row N_NODES
        *(float4*)(xt + N_NODES * 32 + r * 4) = make_float4(0.f, 0.f, 0.f, 0.f);
    }
}

// Kernel 2: block = (p, j-half), 512 threads = 8 waves; wave wv owns
// j = 8*jh + wv (n = p + 625*j). Weight loads 64-float contiguous per wave
// instruction (the r6 win); 1250 blocks -> 2% tail imbalance (r8).
// NEW (v10): the 512 rows are processed as TWO 256-row halves (= d-halves,
// accumulated in the same acc registers - no partial buffers). The half-1
// gather is ISSUED into registers right after the first barrier and committed
// to the second LDS buffer only after 4 full ds-steps (~10k cyc slack >> 900
// cyc HBM latency) -> gather runs concurrently with DS reads + weight HBM
// stream, unlike r2-r8's serial gather->sync->compute (and unlike r9, whose
// per-64-row barriers exposed the gather chain 8x). 2 barriers per block.
// LDS 2 x 36864 B = 73.7 KB -> 2 blocks/CU, 16 waves/CU.
__global__ __launch_bounds__(512, 4) void lcg_main(
    const float* __restrict__ xt,     // [N+1][32]
    const int*   __restrict__ edges,  // [E]
    const float* __restrict__ w,      // [4][E][16]
    float*       __restrict__ out)    // [8][N][16]
{
    __shared__ float lx[2][256 * LX_STRIDE];   // 2 x 36864 B

    int bid = blockIdx.x;
    int p   = bid >> 1;               // 0..624
    int jh  = bid & 1;                // j-half
    int t   = threadIdx.x;

    // gather mapping: thread t -> float4 slot sub of rows rg + 64k (k<4)
    int sub = t & 7;
    int rg  = t >> 3;                 // 0..63
    const int* ep = edges + 512 * p;

    // compute mapping
    int lane = t & 63;
    int wv   = t >> 6;                // 0..7
    int c    = lane & 15;
    int dq   = lane >> 4;             // 0..3 : handles d = 4*ds + dq
    int n    = p + P_COUNT * (8 * jh + wv);

    // weight address: w[i][32n + (4ds+dq)][c] = base_i + n*512 + 64*ds + lane
    const float* wb = w + n * (DEG * CH) + lane;

    float acc[BATCH];
#pragma unroll
    for (int b = 0; b < BATCH; b++) acc[b] = 0.0f;

    // ---- prologue: gather half 0 (rows s=0..255) into buf 0 ----
#pragma unroll
    for (int k = 0; k < 4; k++) {
        int r  = rg + 64 * k;
        int nd = ep[r];
        float4 g = *(const float4*)(xt + nd * 32 + sub * 4);
        *(float4*)(&lx[0][r * LX_STRIDE + sub * 4]) = g;
    }
    __syncthreads();

    // ---- issue half-1 gather into registers (commits after compute) ----
    int ndn[4];
#pragma unroll
    for (int k = 0; k < 4; k++) ndn[k] = ep[256 + rg + 64 * k];
    float4 gn[4];
#pragma unroll
    for (int k = 0; k < 4; k++)
        gn[k] = *(const float4*)(xt + ndn[k] * 32 + sub * 4);

    // ---- compute half 0: ds = 0..3 (d = 4ds+dq in [0,16)) ----
#pragma unroll
    for (int dsl = 0; dsl < 4; dsl++) {
        float w0 = wb[64 * dsl];
        float w1 = wb[64 * dsl + WI_STRIDE];
        float w2 = wb[64 * dsl + 2 * WI_STRIDE];
        float w3 = wb[64 * dsl + 3 * WI_STRIDE];
        const float* lr = &lx[0][(64 * dsl + 16 * dq + c) * LX_STRIDE];
#pragma unroll
        for (int b = 0; b < BATCH; b++) {
            float4 xq = *(const float4*)(lr + 4 * b);
            acc[b] += xq.x * w0 + xq.y * w1 + xq.z * w2 + xq.w * w3;
        }
    }

    // ---- commit half 1 to buf 1 ----
#pragma unroll
    for (int k = 0; k < 4; k++)
        *(float4*)(&lx[1][(rg + 64 * k) * LX_STRIDE + sub * 4]) = gn[k];
    __syncthreads();

    // ---- compute half 1: ds = 4..7 (d = 4ds+dq in [16,32)) ----
#pragma unroll
    for (int dsl = 0; dsl < 4; dsl++) {
        int ds = 4 + dsl;
        float w0 = wb[64 * ds];
        float w1 = wb[64 * ds + WI_STRIDE];
        float w2 = wb[64 * ds + 2 * WI_STRIDE];
        float w3 = wb[64 * ds + 3 * WI_STRIDE];
        const float* lr = &lx[1][(64 * dsl + 16 * dq + c) * LX_STRIDE];
#pragma unroll
        for (int b = 0; b < BATCH; b++) {
            float4 xq = *(const float4*)(lr + 4 * b);
            acc[b] += xq.x * w0 + xq.y * w1 + xq.z * w2 + xq.w * w3;
        }
    }

    // reduce over dq groups (lanes l, l^16, l^32, l^48)
#pragma unroll
    for (int b = 0; b < BATCH; b++) {
        acc[b] += __shfl_xor(acc[b], 16, 64);
        acc[b] += __shfl_xor(acc[b], 32, 64);
    }

    // dq group g stores batches {2g, 2g+1} (16 c-lanes = one 64 B line per b)
    int ob = n * CH + c;
    out[(2 * dq + 0) * (N_NODES * CH) + ob] = acc[2 * dq + 0];
    out[(2 * dq + 1) * (N_NODES * CH) + ob] = acc[2 * dq + 1];
}

extern "C" void kernel_launch(void* const* d_in, const int* in_sizes, int n_in,
                              void* d_out, int out_size, void* d_ws, size_t ws_size,
                              hipStream_t stream) {
    const float* x     = (const float*)d_in[0];   // [8][10000][4] f32
    const int*   edges = (const int*)d_in[1];     // [320000] int
    const float* w     = (const float*)d_in[2];   // [4][320000][16] f32
    float* out = (float*)d_out;                   // [8][10000][16] f32
    float* xt  = (float*)d_ws;                    // (10001*32) floats = 1.28 MB

    int tr_total  = BATCH * N_NODES + 8;                  // 80008
    int tr_blocks = (tr_total + 255) / 256;               // 313
    lcg_transpose<<<tr_blocks, 256, 0, stream>>>(x, xt);

    lcg_main<<<2 * P_COUNT, 512, 0, stream>>>(xt, edges, w, out);
}